// Round 1
// baseline (756.380 us; speedup 1.0000x reference)
//
#include <hip/hip_runtime.h>
#include <hip/hip_bf16.h>

typedef unsigned int u32;
typedef unsigned long long u64;

#define BB 16
#define NA 5
#define NC 20
#define HF 19
#define WF 19
#define NPIX 361        // 19*19
#define NB 1805         // NA*NPIX boxes per batch
#define NW32 58         // ceil(1805/32)
#define NW64 29         // ceil(1805/64)
#define NBC (BB*NC)     // 320 (batch,class) pairs
#define PROB_ELEMS (BB*NB*NC)   // 577600
#define NMS_TH 0.45f

__constant__ float c_bias[10] = {1.08f, 1.19f, 3.42f, 4.41f, 6.63f,
                                 11.38f, 9.42f, 5.11f, 16.62f, 10.52f};

__device__ __forceinline__ float sigmoidf_(float v) {
    return 1.0f / (1.0f + expf(-v));
}

// ---------------------------------------------------------------------------
// Kernel 1: decode boxes (-> d_out boxes section) and scores (-> ws)
// one thread per (b, n);  n = a*361 + gy*19 + gx
// ---------------------------------------------------------------------------
__global__ __launch_bounds__(256) void decode_kernel(
        const float* __restrict__ x, const float* __restrict__ im_info,
        float* __restrict__ boxes_out, float* __restrict__ scores) {
    int tid = blockIdx.x * blockDim.x + threadIdx.x;
    if (tid >= BB * NB) return;
    int b = tid / NB;
    int n = tid % NB;
    int a = n / NPIX;
    int r = n % NPIX;
    int gy = r / WF;
    int gx = r % WF;

    const float* xb = x + (size_t)b * 125 * NPIX + r;   // channel stride NPIX
    float tx = xb[(2 * a + 0) * NPIX];
    float ty = xb[(2 * a + 1) * NPIX];
    float tw = xb[(10 + 2 * a) * NPIX];
    float th = xb[(11 + 2 * a) * NPIX];
    float to = xb[(20 + a) * NPIX];

    float sx = sigmoidf_(tx);
    float sy = sigmoidf_(ty);
    float obj = sigmoidf_(to);

    float im_h = im_info[b * 2 + 0];
    float im_w = im_info[b * 2 + 1];

    float bx = ((sx + (float)gx) / (float)WF) * im_w;
    float by = ((sy + (float)gy) / (float)HF) * im_h;
    float bw = ((expf(tw) * c_bias[2 * a + 0]) / (float)WF) * im_w;
    float bh = ((expf(th) * c_bias[2 * a + 1]) / (float)HF) * im_h;

    float4 bbx = make_float4(bx, by, bw, bh);
    reinterpret_cast<float4*>(boxes_out)[tid] = bbx;

    // softmax over 20 classes * obj  -> scores[(b*NC + c)*NB + n]
    float cv[NC];
    float m = -1e30f;
    #pragma unroll
    for (int c = 0; c < NC; ++c) {
        cv[c] = xb[(25 + NC * a + c) * NPIX];
        m = fmaxf(m, cv[c]);
    }
    float sum = 0.0f;
    #pragma unroll
    for (int c = 0; c < NC; ++c) {
        cv[c] = expf(cv[c] - m);
        sum += cv[c];
    }
    #pragma unroll
    for (int c = 0; c < NC; ++c) {
        scores[((size_t)b * NC + c) * NB + n] = (cv[c] / sum) * obj;
    }
}

// ---------------------------------------------------------------------------
// Kernel 2: per-batch IoU threshold bitmask.  One wave per (b, row i).
// M64[(b*NB + i)*NW64 + t] bit j%64 of word j/64  <=>  iou(i,j) > 0.45
// ---------------------------------------------------------------------------
__global__ __launch_bounds__(64) void iou_mask_kernel(
        const float* __restrict__ boxes, u64* __restrict__ M64) {
    int row = blockIdx.x;              // 0 .. BB*NB-1
    int b = row / NB;
    int i = row % NB;
    int lane = threadIdx.x;

    const float4* bb = reinterpret_cast<const float4*>(boxes) + (size_t)b * NB;
    float4 bi = bb[i];
    float ax1 = bi.x - bi.z * 0.5f, ax2 = bi.x + bi.z * 0.5f;
    float ay1 = bi.y - bi.w * 0.5f, ay2 = bi.y + bi.w * 0.5f;
    float aarea = bi.z * bi.w;

    u64 myword = 0;
    #pragma unroll 4
    for (int t = 0; t < NW64; ++t) {
        int j = t * 64 + lane;
        int jc = j < NB ? j : NB - 1;
        float4 bj = bb[jc];
        float bx1 = bj.x - bj.z * 0.5f, bx2 = bj.x + bj.z * 0.5f;
        float by1 = bj.y - bj.w * 0.5f, by2 = bj.y + bj.w * 0.5f;
        float barea = bj.z * bj.w;
        float iw = fmaxf(fminf(ax2, bx2) - fmaxf(ax1, bx1), 0.0f);
        float ih = fmaxf(fminf(ay2, by2) - fmaxf(ay1, by1), 0.0f);
        float inter = iw * ih;
        float iou = inter / (aarea + barea - inter + 1e-9f);
        bool pred = (iou > NMS_TH) && (j < NB);
        u64 mask = __ballot(pred);
        if (lane == t) myword = mask;
    }
    if (lane < NW64) M64[(size_t)row * NW64 + lane] = myword;
}

// ---------------------------------------------------------------------------
// Kernel 3: stable descending argsort per (b,c) via bitonic sort of u64 keys.
// key = (score_bits << 32) | (2047 - idx); scores strictly > 0 so float bits
// are order-preserving as unsigned.  Padding keys = 0 sort last.
// ---------------------------------------------------------------------------
__global__ __launch_bounds__(256) void sort_kernel(
        const float* __restrict__ scores, u32* __restrict__ order) {
    int bc = blockIdx.x;               // 0 .. NBC-1
    __shared__ u64 keys[2048];
    const float* s = scores + (size_t)bc * NB;

    for (int t = threadIdx.x; t < 2048; t += 256) {
        u64 k = 0;
        if (t < NB) {
            u32 sb = __float_as_uint(s[t]);
            k = ((u64)sb << 32) | (u64)(2047 - t);
        }
        keys[t] = k;
    }
    __syncthreads();

    for (int k = 2; k <= 2048; k <<= 1) {
        for (int j = k >> 1; j > 0; j >>= 1) {
            for (int t = threadIdx.x; t < 2048; t += 256) {
                int ixj = t ^ j;
                if (ixj > t) {
                    u64 a = keys[t], b = keys[ixj];
                    bool desc = ((t & k) == 0);
                    bool sw = desc ? (a < b) : (a > b);
                    if (sw) { keys[t] = b; keys[ixj] = a; }
                }
            }
            __syncthreads();
        }
    }

    for (int t = threadIdx.x; t < NB; t += 256)
        order[(size_t)bc * NB + t] = 2047u - (u32)(keys[t] & 0xFFFFFFFFull);
}

// ---------------------------------------------------------------------------
// Kernel 4: serial greedy NMS scan, one wave per (b,c).
// removed-bitmask lives distributed: lane w (w<58) owns u32 word w.
// Wave-uniform bit test via readlane; kept rows OR their M row in.
// Depth-8 register prefetch of M rows hides L2 latency on the serial chain.
// ---------------------------------------------------------------------------
__global__ __launch_bounds__(64) void nms_scan_kernel(
        const u32* __restrict__ order, const u32* __restrict__ M32,
        u32* __restrict__ keep) {
    int bc = blockIdx.x;
    int b = bc / NC;
    int lane = threadIdx.x;
    const u32* ord = order + (size_t)bc * NB;
    const u32* Mb = M32 + (size_t)b * NB * NW32;

    __shared__ u32 sord[NB];
    for (int t = lane; t < NB; t += 64) sord[t] = ord[t];
    __syncthreads();

    u32 rw = 0;    // removed word (lane-owned)
    u32 kw = 0;    // keep word (lane-owned)

    constexpr int D = 8;
    u32 mbuf[D];
    #pragma unroll
    for (int d = 0; d < D; ++d) {
        u32 idx = sord[d];
        mbuf[d] = (lane < NW32) ? Mb[idx * NW32 + lane] : 0u;
    }

    for (int i = 0; i < NB; i += D) {
        #pragma unroll
        for (int d = 0; d < D; ++d) {
            int ii = i + d;
            if (ii < NB) {
                u32 idx = sord[ii];
                u32 m = mbuf[d];
                int nn = ii + D;
                if (nn < NB) {
                    u32 nidx = sord[nn];
                    mbuf[d] = (lane < NW32) ? Mb[nidx * NW32 + lane] : 0u;
                }
                u32 curw = (u32)__builtin_amdgcn_readlane((int)rw, (int)(idx >> 5));
                if (((curw >> (idx & 31u)) & 1u) == 0u) {
                    if (lane == (int)(idx >> 5)) kw |= (1u << (idx & 31u));
                    rw |= m;
                }
            }
        }
    }
    if (lane < NW32) keep[(size_t)bc * NW32 + lane] = kw;
}

// ---------------------------------------------------------------------------
// Kernel 5: prob[b][n][c] = keep_bit(b,c,n) ? scores[b][c][n] : 0
// ---------------------------------------------------------------------------
__global__ __launch_bounds__(256) void finalize_kernel(
        const float* __restrict__ scores, const u32* __restrict__ keep,
        float* __restrict__ prob) {
    int tid = blockIdx.x * blockDim.x + threadIdx.x;
    if (tid >= PROB_ELEMS) return;
    int c = tid % NC;
    int t2 = tid / NC;
    int n = t2 % NB;
    int b = t2 / NB;
    int bc = b * NC + c;
    u32 w = keep[(size_t)bc * NW32 + (n >> 5)];
    float s = scores[(size_t)bc * NB + n];
    prob[tid] = ((w >> (n & 31)) & 1u) ? s : 0.0f;
}

// ---------------------------------------------------------------------------
extern "C" void kernel_launch(void* const* d_in, const int* in_sizes, int n_in,
                              void* d_out, int out_size, void* d_ws, size_t ws_size,
                              hipStream_t stream) {
    const float* x = (const float*)d_in[0];        // (16,125,19,19)
    const float* im_info = (const float*)d_in[1];  // (16,2)

    float* prob_out = (float*)d_out;                       // 577600 floats
    float* boxes_out = prob_out + PROB_ELEMS;              // 115520 floats

    // workspace layout
    float* scores = (float*)d_ws;                          // 577600 f32
    u32* order = (u32*)(scores + PROB_ELEMS);              // 577600 u32
    char* mbase = (char*)d_ws + (size_t)2 * PROB_ELEMS * 4;
    u64* M64 = (u64*)mbase;                                // 16*1805*29 u64
    u32* M32 = (u32*)mbase;
    u32* keep = (u32*)(mbase + (size_t)BB * NB * NW64 * 8); // 320*58 u32

    int nthreads = BB * NB;   // 28880
    decode_kernel<<<(nthreads + 255) / 256, 256, 0, stream>>>(
        x, im_info, boxes_out, scores);

    iou_mask_kernel<<<BB * NB, 64, 0, stream>>>(boxes_out, M64);

    sort_kernel<<<NBC, 256, 0, stream>>>(scores, order);

    nms_scan_kernel<<<NBC, 64, 0, stream>>>(order, M32, keep);

    finalize_kernel<<<(PROB_ELEMS + 255) / 256, 256, 0, stream>>>(
        scores, keep, prob_out);
}

// Round 2
// 329.084 us; speedup vs baseline: 2.2984x; 2.2984x over previous
//
#include <hip/hip_runtime.h>
#include <hip/hip_bf16.h>

typedef unsigned int u32;
typedef unsigned long long u64;

#define BB 16
#define NA 5
#define NC 20
#define HF 19
#define WF 19
#define NPIX 361        // 19*19
#define NB 1805         // NA*NPIX boxes per batch
#define NW32 58         // ceil(1805/32)
#define NW64 29         // ceil(1805/64)
#define NBC (BB*NC)     // 320 (batch,class) pairs
#define PROB_ELEMS (BB*NB*NC)   // 577600
#define NMS_TH 0.45f

__constant__ float c_bias[10] = {1.08f, 1.19f, 3.42f, 4.41f, 6.63f,
                                 11.38f, 9.42f, 5.11f, 16.62f, 10.52f};

__device__ __forceinline__ float sigmoidf_(float v) {
    return 1.0f / (1.0f + expf(-v));
}

// ---------------------------------------------------------------------------
// Kernel 1: decode boxes (-> d_out boxes section) and scores (-> ws)
// one thread per (b, n);  n = a*361 + gy*19 + gx
// ---------------------------------------------------------------------------
__global__ __launch_bounds__(256) void decode_kernel(
        const float* __restrict__ x, const float* __restrict__ im_info,
        float* __restrict__ boxes_out, float* __restrict__ scores) {
    int tid = blockIdx.x * blockDim.x + threadIdx.x;
    if (tid >= BB * NB) return;
    int b = tid / NB;
    int n = tid % NB;
    int a = n / NPIX;
    int r = n % NPIX;
    int gy = r / WF;
    int gx = r % WF;

    const float* xb = x + (size_t)b * 125 * NPIX + r;   // channel stride NPIX
    float tx = xb[(2 * a + 0) * NPIX];
    float ty = xb[(2 * a + 1) * NPIX];
    float tw = xb[(10 + 2 * a) * NPIX];
    float th = xb[(11 + 2 * a) * NPIX];
    float to = xb[(20 + a) * NPIX];

    float sx = sigmoidf_(tx);
    float sy = sigmoidf_(ty);
    float obj = sigmoidf_(to);

    float im_h = im_info[b * 2 + 0];
    float im_w = im_info[b * 2 + 1];

    float bx = ((sx + (float)gx) / (float)WF) * im_w;
    float by = ((sy + (float)gy) / (float)HF) * im_h;
    float bw = ((expf(tw) * c_bias[2 * a + 0]) / (float)WF) * im_w;
    float bh = ((expf(th) * c_bias[2 * a + 1]) / (float)HF) * im_h;

    float4 bbx = make_float4(bx, by, bw, bh);
    reinterpret_cast<float4*>(boxes_out)[tid] = bbx;

    // softmax over 20 classes * obj  -> scores[(b*NC + c)*NB + n]
    float cv[NC];
    float m = -1e30f;
    #pragma unroll
    for (int c = 0; c < NC; ++c) {
        cv[c] = xb[(25 + NC * a + c) * NPIX];
        m = fmaxf(m, cv[c]);
    }
    float sum = 0.0f;
    #pragma unroll
    for (int c = 0; c < NC; ++c) {
        cv[c] = expf(cv[c] - m);
        sum += cv[c];
    }
    #pragma unroll
    for (int c = 0; c < NC; ++c) {
        scores[((size_t)b * NC + c) * NB + n] = (cv[c] / sum) * obj;
    }
}

// ---------------------------------------------------------------------------
// Kernel 2: per-batch IoU threshold bitmask.  One wave per (b, row i).
// M64[(b*NB + i)*NW64 + t] bit j%64 of word j/64  <=>  iou(i,j) > 0.45
// ---------------------------------------------------------------------------
__global__ __launch_bounds__(64) void iou_mask_kernel(
        const float* __restrict__ boxes, u64* __restrict__ M64) {
    int row = blockIdx.x;              // 0 .. BB*NB-1
    int b = row / NB;
    int i = row % NB;
    int lane = threadIdx.x;

    const float4* bb = reinterpret_cast<const float4*>(boxes) + (size_t)b * NB;
    float4 bi = bb[i];
    float ax1 = bi.x - bi.z * 0.5f, ax2 = bi.x + bi.z * 0.5f;
    float ay1 = bi.y - bi.w * 0.5f, ay2 = bi.y + bi.w * 0.5f;
    float aarea = bi.z * bi.w;

    u64 myword = 0;
    #pragma unroll 4
    for (int t = 0; t < NW64; ++t) {
        int j = t * 64 + lane;
        int jc = j < NB ? j : NB - 1;
        float4 bj = bb[jc];
        float bx1 = bj.x - bj.z * 0.5f, bx2 = bj.x + bj.z * 0.5f;
        float by1 = bj.y - bj.w * 0.5f, by2 = bj.y + bj.w * 0.5f;
        float barea = bj.z * bj.w;
        float iw = fmaxf(fminf(ax2, bx2) - fmaxf(ax1, bx1), 0.0f);
        float ih = fmaxf(fminf(ay2, by2) - fmaxf(ay1, by1), 0.0f);
        float inter = iw * ih;
        float iou = inter / (aarea + barea - inter + 1e-9f);
        bool pred = (iou > NMS_TH) && (j < NB);
        u64 mask = __ballot(pred);
        if (lane == t) myword = mask;
    }
    if (lane < NW64) M64[(size_t)row * NW64 + lane] = myword;
}

// ---------------------------------------------------------------------------
// Kernel 3: stable descending argsort per (b,c) via bitonic sort of u64 keys.
// key = (score_bits << 32) | (2047 - idx); scores strictly > 0 so float bits
// are order-preserving as unsigned.  Padding keys = 0 sort last.
// ---------------------------------------------------------------------------
__global__ __launch_bounds__(256) void sort_kernel(
        const float* __restrict__ scores, u32* __restrict__ order) {
    int bc = blockIdx.x;               // 0 .. NBC-1
    __shared__ u64 keys[2048];
    const float* s = scores + (size_t)bc * NB;

    for (int t = threadIdx.x; t < 2048; t += 256) {
        u64 k = 0;
        if (t < NB) {
            u32 sb = __float_as_uint(s[t]);
            k = ((u64)sb << 32) | (u64)(2047 - t);
        }
        keys[t] = k;
    }
    __syncthreads();

    for (int k = 2; k <= 2048; k <<= 1) {
        for (int j = k >> 1; j > 0; j >>= 1) {
            for (int t = threadIdx.x; t < 2048; t += 256) {
                int ixj = t ^ j;
                if (ixj > t) {
                    u64 a = keys[t], b = keys[ixj];
                    bool desc = ((t & k) == 0);
                    bool sw = desc ? (a < b) : (a > b);
                    if (sw) { keys[t] = b; keys[ixj] = a; }
                }
            }
            __syncthreads();
        }
    }

    for (int t = threadIdx.x; t < NB; t += 256)
        order[(size_t)bc * NB + t] = 2047u - (u32)(keys[t] & 0xFFFFFFFFull);
}

// ---------------------------------------------------------------------------
// Kernel 4: serial greedy NMS scan, one wave per (b,c).
// Double-buffered LDS staging of 64 sorted M-rows per chunk via
// global_load_lds (no VGPR writeback -> no per-load waitcnt; one drain per
// chunk at __syncthreads, overlapped with the scan of the previous chunk).
// removed-bitmask distributed: lane w (w<58) owns u32 word w of rw.
// ---------------------------------------------------------------------------
__global__ __launch_bounds__(64) void nms_scan_kernel(
        const u32* __restrict__ order, const u32* __restrict__ M32,
        u32* __restrict__ keep) {
    int bc = blockIdx.x;
    int b = bc / NC;
    int lane = threadIdx.x;
    const u32* ord = order + (size_t)bc * NB;
    const u32* Mb = M32 + (size_t)b * NB * NW32;

    __shared__ u32 rows[2][64 * 64];   // [buf][row d][word lane], 32 KB

    constexpr int NCHUNK = (NB + 63) / 64;   // 29

    u32 rw = 0;    // removed word (lane-owned)
    u32 kw = 0;    // keep word (lane-owned)

    // sorted indices for chunk 0 and 1 (positions 0..127 all < NB)
    u32 sidx_cur = ord[lane];
    u32 sidx_next = ord[64 + lane];

    // stage chunk 0 into buffer 0
    #pragma unroll
    for (int d = 0; d < 64; ++d) {
        u32 idx = (u32)__builtin_amdgcn_readlane((int)sidx_cur, d);
        idx = idx < NB ? idx : (NB - 1);
        const u32* rowp = Mb + (size_t)idx * NW32 + lane;  // lanes 58..63 read <=24B past row (safe)
        __builtin_amdgcn_global_load_lds(
            (const __attribute__((address_space(1))) void*)rowp,
            (__attribute__((address_space(3))) void*)&rows[0][d * 64],
            4, 0, 0);
    }
    __syncthreads();

    int cur = 0;
    for (int c = 0; c < NCHUNK; ++c) {
        // stage chunk c+1 into the other buffer (overlaps with scan below)
        if (c + 1 < NCHUNK) {
            #pragma unroll
            for (int d = 0; d < 64; ++d) {
                u32 idx = (u32)__builtin_amdgcn_readlane((int)sidx_next, d);
                idx = idx < NB ? idx : (NB - 1);   // clamp padded/garbage tail
                const u32* rowp = Mb + (size_t)idx * NW32 + lane;
                __builtin_amdgcn_global_load_lds(
                    (const __attribute__((address_space(1))) void*)rowp,
                    (__attribute__((address_space(3))) void*)&rows[cur ^ 1][d * 64],
                    4, 0, 0);
            }
        }
        // prefetch sorted indices for chunk c+2 (clamped address, stays in-array)
        u32 sidx_next2 = sidx_next;
        if (c + 2 < NCHUNK) {
            int p = (c + 2) * 64 + lane;
            p = p < NB ? p : (NB - 1);
            sidx_next2 = ord[p];
        }

        // serial scan of chunk c from LDS
        int base = c * 64;
        #pragma unroll
        for (int d = 0; d < 64; ++d) {
            u32 idx = (u32)__builtin_amdgcn_readlane((int)sidx_cur, d);
            u32 rowword = rows[cur][d * 64 + lane];
            u32 iwd = idx >> 5;
            u32 ib = idx & 31u;
            bool mylane = ((u32)lane == iwd);
            bool bitset = ((rw >> ib) & 1u) != 0u;
            u64 sup = __ballot(mylane && bitset);
            if (sup == 0 && (base + d) < NB) {
                rw |= rowword;
                if (mylane) kw |= (1u << ib);
            }
        }
        __syncthreads();   // drains staging of chunk c+1, orders LDS
        cur ^= 1;
        sidx_cur = sidx_next;
        sidx_next = sidx_next2;
    }
    if (lane < NW32) keep[(size_t)bc * NW32 + lane] = kw;
}

// ---------------------------------------------------------------------------
// Kernel 5: prob[b][n][c] = keep_bit(b,c,n) ? scores[b][c][n] : 0
// ---------------------------------------------------------------------------
__global__ __launch_bounds__(256) void finalize_kernel(
        const float* __restrict__ scores, const u32* __restrict__ keep,
        float* __restrict__ prob) {
    int tid = blockIdx.x * blockDim.x + threadIdx.x;
    if (tid >= PROB_ELEMS) return;
    int c = tid % NC;
    int t2 = tid / NC;
    int n = t2 % NB;
    int b = t2 / NB;
    int bc = b * NC + c;
    u32 w = keep[(size_t)bc * NW32 + (n >> 5)];
    float s = scores[(size_t)bc * NB + n];
    prob[tid] = ((w >> (n & 31)) & 1u) ? s : 0.0f;
}

// ---------------------------------------------------------------------------
extern "C" void kernel_launch(void* const* d_in, const int* in_sizes, int n_in,
                              void* d_out, int out_size, void* d_ws, size_t ws_size,
                              hipStream_t stream) {
    const float* x = (const float*)d_in[0];        // (16,125,19,19)
    const float* im_info = (const float*)d_in[1];  // (16,2)

    float* prob_out = (float*)d_out;                       // 577600 floats
    float* boxes_out = prob_out + PROB_ELEMS;              // 115520 floats

    // workspace layout
    float* scores = (float*)d_ws;                          // 577600 f32
    u32* order = (u32*)(scores + PROB_ELEMS);              // 577600 u32
    char* mbase = (char*)d_ws + (size_t)2 * PROB_ELEMS * 4;
    u64* M64 = (u64*)mbase;                                // 16*1805*29 u64
    u32* M32 = (u32*)mbase;
    u32* keep = (u32*)(mbase + (size_t)BB * NB * NW64 * 8); // 320*58 u32

    int nthreads = BB * NB;   // 28880
    decode_kernel<<<(nthreads + 255) / 256, 256, 0, stream>>>(
        x, im_info, boxes_out, scores);

    iou_mask_kernel<<<BB * NB, 64, 0, stream>>>(boxes_out, M64);

    sort_kernel<<<NBC, 256, 0, stream>>>(scores, order);

    nms_scan_kernel<<<NBC, 64, 0, stream>>>(order, M32, keep);

    finalize_kernel<<<(PROB_ELEMS + 255) / 256, 256, 0, stream>>>(
        scores, keep, prob_out);
}

// Round 3
// 297.459 us; speedup vs baseline: 2.5428x; 1.1063x over previous
//
#include <hip/hip_runtime.h>
#include <hip/hip_bf16.h>

typedef unsigned int u32;
typedef unsigned long long u64;

#define BB 16
#define NA 5
#define NC 20
#define HF 19
#define WF 19
#define NPIX 361        // 19*19
#define NB 1805         // NA*NPIX boxes per batch
#define NW32 58         // ceil(1805/32)
#define NW64 29         // ceil(1805/64)
#define NBC (BB*NC)     // 320 (batch,class) pairs
#define PROB_ELEMS (BB*NB*NC)   // 577600

// Exact-equivalence threshold: RN_f32(inter/denom) > 0.45f
//   <=>  (double)inter > MID * (double)denom
// where MID = midpoint(0.45f, nextup(0.45f)) = 0x1.CCCCCDp-2 (exact in f64;
// 25-bit MID x 24-bit denom product is exact; tie rounds-to-even to 0.45f
// which is NOT > 0.45f, matching the strict > here).
#define IOU_MID 0x1.CCCCCDp-2

__constant__ float c_bias[10] = {1.08f, 1.19f, 3.42f, 4.41f, 6.63f,
                                 11.38f, 9.42f, 5.11f, 16.62f, 10.52f};

__device__ __forceinline__ float sigmoidf_(float v) {
    return 1.0f / (1.0f + expf(-v));
}

// ---------------------------------------------------------------------------
// Kernel 1: decode boxes (-> d_out boxes section), corners+areas (-> ws),
// scores (-> ws).  one thread per (b, n);  n = a*361 + gy*19 + gx
// ---------------------------------------------------------------------------
__global__ __launch_bounds__(256) void decode_kernel(
        const float* __restrict__ x, const float* __restrict__ im_info,
        float* __restrict__ boxes_out, float4* __restrict__ corners,
        float* __restrict__ areas, float* __restrict__ scores) {
    int tid = blockIdx.x * blockDim.x + threadIdx.x;
    if (tid >= BB * NB) return;
    int b = tid / NB;
    int n = tid % NB;
    int a = n / NPIX;
    int r = n % NPIX;
    int gy = r / WF;
    int gx = r % WF;

    const float* xb = x + (size_t)b * 125 * NPIX + r;   // channel stride NPIX
    float tx = xb[(2 * a + 0) * NPIX];
    float ty = xb[(2 * a + 1) * NPIX];
    float tw = xb[(10 + 2 * a) * NPIX];
    float th = xb[(11 + 2 * a) * NPIX];
    float to = xb[(20 + a) * NPIX];

    float sx = sigmoidf_(tx);
    float sy = sigmoidf_(ty);
    float obj = sigmoidf_(to);

    float im_h = im_info[b * 2 + 0];
    float im_w = im_info[b * 2 + 1];

    float bx = ((sx + (float)gx) / (float)WF) * im_w;
    float by = ((sy + (float)gy) / (float)HF) * im_h;
    float bw = ((expf(tw) * c_bias[2 * a + 0]) / (float)WF) * im_w;
    float bh = ((expf(th) * c_bias[2 * a + 1]) / (float)HF) * im_h;

    reinterpret_cast<float4*>(boxes_out)[tid] = make_float4(bx, by, bw, bh);

    // corners exactly as reference computes them from (cx,cy,w,h)
    float x1 = bx - bw * 0.5f, x2 = bx + bw * 0.5f;
    float y1 = by - bh * 0.5f, y2 = by + bh * 0.5f;
    corners[tid] = make_float4(x1, y1, x2, y2);
    areas[tid] = bw * bh;

    // softmax over 20 classes * obj  -> scores[(b*NC + c)*NB + n]
    float cv[NC];
    float m = -1e30f;
    #pragma unroll
    for (int c = 0; c < NC; ++c) {
        cv[c] = xb[(25 + NC * a + c) * NPIX];
        m = fmaxf(m, cv[c]);
    }
    float sum = 0.0f;
    #pragma unroll
    for (int c = 0; c < NC; ++c) {
        cv[c] = expf(cv[c] - m);
        sum += cv[c];
    }
    #pragma unroll
    for (int c = 0; c < NC; ++c) {
        scores[((size_t)b * NC + c) * NB + n] = (cv[c] / sum) * obj;
    }
}

// ---------------------------------------------------------------------------
// Kernel 2: per-batch IoU threshold bitmask.  One wave per (b, row i).
// Uses precomputed corners/areas and the exact f64 midpoint test (no divide).
// ---------------------------------------------------------------------------
__global__ __launch_bounds__(64) void iou_mask_kernel(
        const float4* __restrict__ corners, const float* __restrict__ areas,
        u64* __restrict__ M64) {
    int row = blockIdx.x;              // 0 .. BB*NB-1
    int b = row / NB;
    int i = row % NB;
    int lane = threadIdx.x;

    const float4* cb = corners + (size_t)b * NB;
    const float* ab = areas + (size_t)b * NB;
    float4 ci = cb[i];                 // (x1,y1,x2,y2)
    float aarea = ab[i];

    u64 myword = 0;
    #pragma unroll 4
    for (int t = 0; t < NW64; ++t) {
        int j = t * 64 + lane;
        int jc = j < NB ? j : NB - 1;
        float4 cj = cb[jc];
        float barea = ab[jc];
        float iw = fmaxf(fminf(ci.z, cj.z) - fmaxf(ci.x, cj.x), 0.0f);
        float ih = fmaxf(fminf(ci.w, cj.w) - fmaxf(ci.y, cj.y), 0.0f);
        float inter = iw * ih;
        float denom = aarea + barea - inter + 1e-9f;
        bool pred = ((double)inter > IOU_MID * (double)denom) && (j < NB);
        u64 mask = __ballot(pred);
        if (lane == t) myword = mask;
    }
    if (lane < NW64) M64[(size_t)row * NW64 + lane] = myword;
}

// ---------------------------------------------------------------------------
// Kernel 3: stable descending argsort per (b,c) via bitonic sort of u64 keys.
// key = (score_bits << 32) | (2047 - idx); scores strictly > 0 so float bits
// are order-preserving as unsigned.  Padding keys = 0 sort last.
// ---------------------------------------------------------------------------
__global__ __launch_bounds__(256) void sort_kernel(
        const float* __restrict__ scores, u32* __restrict__ order) {
    int bc = blockIdx.x;               // 0 .. NBC-1
    __shared__ u64 keys[2048];
    const float* s = scores + (size_t)bc * NB;

    for (int t = threadIdx.x; t < 2048; t += 256) {
        u64 k = 0;
        if (t < NB) {
            u32 sb = __float_as_uint(s[t]);
            k = ((u64)sb << 32) | (u64)(2047 - t);
        }
        keys[t] = k;
    }
    __syncthreads();

    for (int k = 2; k <= 2048; k <<= 1) {
        for (int j = k >> 1; j > 0; j >>= 1) {
            for (int t = threadIdx.x; t < 2048; t += 256) {
                int ixj = t ^ j;
                if (ixj > t) {
                    u64 a = keys[t], b = keys[ixj];
                    bool desc = ((t & k) == 0);
                    bool sw = desc ? (a < b) : (a > b);
                    if (sw) { keys[t] = b; keys[ixj] = a; }
                }
            }
            __syncthreads();
        }
    }

    for (int t = threadIdx.x; t < NB; t += 256)
        order[(size_t)bc * NB + t] = 2047u - (u32)(keys[t] & 0xFFFFFFFFull);
}

// ---------------------------------------------------------------------------
// Kernel 4: greedy NMS, one wave per (b,c), chunked by 64 sorted candidates.
// Per chunk: (a) parallel colmask build from staged LDS rows (pipelined
// ds_reads, no serial dep), (b) ds_bpermute pre-check vs global removed mask,
// (c) register/SGPR-only greedy loop (one iter per KEPT box, ~no memory),
// (d) pipelined rw update.  Double-buffered global_load_lds staging.
// blockIdx mapping clusters same-batch blocks on one XCD (b = blk % 16).
// ---------------------------------------------------------------------------
__global__ __launch_bounds__(64) void nms_scan_kernel(
        const u32* __restrict__ order, const u32* __restrict__ M32,
        u32* __restrict__ keep) {
    int blk = blockIdx.x;
    int b = blk % BB;            // blk%8 = XCD -> 2 batches per XCD (L2 locality)
    int cls = blk / BB;
    int bc = b * NC + cls;
    int lane = threadIdx.x;
    const u32* ord = order + (size_t)bc * NB;
    const u32* Mb = M32 + (size_t)b * NB * NW32;

    __shared__ u32 rows[2][64 * 64];   // [buf][row d][word], 32 KB
    __shared__ u32 kws[64];
    kws[lane] = 0;

    constexpr int NCHUNK = (NB + 63) / 64;   // 29

    u32 rw = 0;    // removed word (lane w owns word w, w < NW32)

    u32 sidx_cur = ord[lane];          // positions 0..127 all < NB
    u32 sidx_next = ord[64 + lane];

    // stage chunk 0 into buffer 0
    #pragma unroll
    for (int d = 0; d < 64; ++d) {
        u32 idx = (u32)__builtin_amdgcn_readlane((int)sidx_cur, d);
        idx = idx < NB ? idx : (NB - 1);
        const u32* rowp = Mb + (size_t)idx * NW32 + lane;  // lanes 58..63 read <=24B past row (safe)
        __builtin_amdgcn_global_load_lds(
            (const __attribute__((address_space(1))) void*)rowp,
            (__attribute__((address_space(3))) void*)&rows[0][d * 64],
            4, 0, 0);
    }
    __syncthreads();

    int cur = 0;
    for (int c = 0; c < NCHUNK; ++c) {
        // stage chunk c+1 into the other buffer (overlaps with work below)
        if (c + 1 < NCHUNK) {
            #pragma unroll
            for (int d = 0; d < 64; ++d) {
                u32 idx = (u32)__builtin_amdgcn_readlane((int)sidx_next, d);
                idx = idx < NB ? idx : (NB - 1);
                const u32* rowp = Mb + (size_t)idx * NW32 + lane;
                __builtin_amdgcn_global_load_lds(
                    (const __attribute__((address_space(1))) void*)rowp,
                    (__attribute__((address_space(3))) void*)&rows[cur ^ 1][d * 64],
                    4, 0, 0);
            }
        }
        // prefetch sorted indices for chunk c+2
        u32 sidx_next2 = sidx_next;
        if (c + 2 < NCHUNK) {
            int p = (c + 2) * 64 + lane;
            p = p < NB ? p : (NB - 1);
            sidx_next2 = ord[p];
        }

        u32 idx = sidx_cur < NB ? sidx_cur : (NB - 1);
        u32 we = idx >> 5;
        u32 be = idx & 31u;
        bool valid = (c * 64 + lane) < NB;

        // pre-suppression: bit idx of global removed mask (word we lives on lane we)
        u32 wv = (u32)__builtin_amdgcn_ds_bpermute((int)(we << 2), (int)rw);
        bool pre = ((wv >> be) & 1u) != 0u;

        // column mask: col bit d = M[idx_d][idx_e]  (independent LDS reads)
        const u32* rbase = &rows[cur][0];
        u32 collo = 0, colhi = 0;
        #pragma unroll
        for (int d = 0; d < 32; ++d) {
            u32 w = rbase[d * 64 + we];
            collo |= ((w >> be) & 1u) << d;
        }
        #pragma unroll
        for (int d = 0; d < 32; ++d) {
            u32 w = rbase[(d + 32) * 64 + we];
            colhi |= ((w >> be) & 1u) << d;
        }
        u64 col = ((u64)colhi << 32) | (u64)collo;

        // serial greedy over this chunk — registers/SGPRs only
        u64 act = __ballot(valid && !pre);
        u64 kept = 0;
        while (act) {
            int d = __builtin_ctzll(act);
            kept |= (1ull << d);
            bool s = ((col >> d) & 1ull) != 0ull;
            u64 sup = __ballot(s);
            act &= ~(sup | (1ull << d));
        }

        // record kept boxes into the keep bitmask (scatter via LDS atomics)
        if ((kept >> lane) & 1ull) atomicOr(&kws[we], 1u << be);

        // fold kept rows into the global removed mask (pipelined reads)
        u64 km = kept;
        while (km) {
            int d = __builtin_ctzll(km);
            km &= km - 1;
            rw |= rbase[d * 64 + lane];
        }

        __syncthreads();   // drains staging of chunk c+1; orders buffer reuse
        cur ^= 1;
        sidx_cur = sidx_next;
        sidx_next = sidx_next2;
    }
    __syncthreads();
    if (lane < NW32) keep[(size_t)bc * NW32 + lane] = kws[lane];
}

// ---------------------------------------------------------------------------
// Kernel 5: prob[b][n][c] = keep_bit(b,c,n) ? scores[b][c][n] : 0
// ---------------------------------------------------------------------------
__global__ __launch_bounds__(256) void finalize_kernel(
        const float* __restrict__ scores, const u32* __restrict__ keep,
        float* __restrict__ prob) {
    int tid = blockIdx.x * blockDim.x + threadIdx.x;
    if (tid >= PROB_ELEMS) return;
    int c = tid % NC;
    int t2 = tid / NC;
    int n = t2 % NB;
    int b = t2 / NB;
    int bc = b * NC + c;
    u32 w = keep[(size_t)bc * NW32 + (n >> 5)];
    float s = scores[(size_t)bc * NB + n];
    prob[tid] = ((w >> (n & 31)) & 1u) ? s : 0.0f;
}

// ---------------------------------------------------------------------------
extern "C" void kernel_launch(void* const* d_in, const int* in_sizes, int n_in,
                              void* d_out, int out_size, void* d_ws, size_t ws_size,
                              hipStream_t stream) {
    const float* x = (const float*)d_in[0];        // (16,125,19,19)
    const float* im_info = (const float*)d_in[1];  // (16,2)

    float* prob_out = (float*)d_out;                       // 577600 floats
    float* boxes_out = prob_out + PROB_ELEMS;              // 115520 floats

    // workspace layout
    float* scores = (float*)d_ws;                           // 577600 f32
    u32* order = (u32*)(scores + PROB_ELEMS);               // 577600 u32
    char* mbase = (char*)d_ws + (size_t)2 * PROB_ELEMS * 4;
    u64* M64 = (u64*)mbase;                                 // 16*1805*29 u64
    u32* M32 = (u32*)mbase;
    char* kbase = mbase + (size_t)BB * NB * NW64 * 8;
    u32* keep = (u32*)kbase;                                // 320*58 u32
    float4* corners = (float4*)(kbase + (size_t)NBC * NW32 * 4 + 256);
    float* areas = (float*)(corners + (size_t)BB * NB);     // 28880 f32

    int nthreads = BB * NB;   // 28880
    decode_kernel<<<(nthreads + 255) / 256, 256, 0, stream>>>(
        x, im_info, boxes_out, corners, areas, scores);

    iou_mask_kernel<<<BB * NB, 64, 0, stream>>>(corners, areas, M64);

    sort_kernel<<<NBC, 256, 0, stream>>>(scores, order);

    nms_scan_kernel<<<NBC, 64, 0, stream>>>(order, M32, keep);

    finalize_kernel<<<(PROB_ELEMS + 255) / 256, 256, 0, stream>>>(
        scores, keep, prob_out);
}

// Round 4
// 225.619 us; speedup vs baseline: 3.3525x; 1.3184x over previous
//
#include <hip/hip_runtime.h>
#include <hip/hip_bf16.h>

typedef unsigned int u32;
typedef unsigned long long u64;

#define BB 16
#define NA 5
#define NC 20
#define HF 19
#define WF 19
#define NPIX 361        // 19*19
#define NB 1805         // NA*NPIX boxes per batch
#define NW32 58         // ceil(1805/32)
#define NW64 29         // ceil(1805/64)
#define MS64 32         // padded M row stride in u64 (256 B rows)
#define MS32 64         // padded M row stride in u32
#define NBC (BB*NC)     // 320 (batch,class) pairs
#define PROB_ELEMS (BB*NB*NC)   // 577600

// Exact-equivalence threshold: RN_f32(inter/denom) > 0.45f
//   <=>  (double)inter > MID * (double)denom
// where MID = midpoint(0.45f, nextup(0.45f)) = 0x1.CCCCCDp-2 (exact in f64;
// 25-bit MID x 24-bit denom product is exact; tie rounds-to-even to 0.45f
// which is NOT > 0.45f, matching the strict > here).
#define IOU_MID 0x1.CCCCCDp-2

__constant__ float c_bias[10] = {1.08f, 1.19f, 3.42f, 4.41f, 6.63f,
                                 11.38f, 9.42f, 5.11f, 16.62f, 10.52f};

__device__ __forceinline__ float sigmoidf_(float v) {
    return 1.0f / (1.0f + expf(-v));
}

// ---------------------------------------------------------------------------
// Kernel 1: decode boxes (-> d_out boxes section), corners+areas (-> ws,
// aliased over the not-yet-written `order` region), scores (-> ws).
// ---------------------------------------------------------------------------
__global__ __launch_bounds__(256) void decode_kernel(
        const float* __restrict__ x, const float* __restrict__ im_info,
        float* __restrict__ boxes_out, float4* __restrict__ corners,
        float* __restrict__ areas, float* __restrict__ scores) {
    int tid = blockIdx.x * blockDim.x + threadIdx.x;
    if (tid >= BB * NB) return;
    int b = tid / NB;
    int n = tid % NB;
    int a = n / NPIX;
    int r = n % NPIX;
    int gy = r / WF;
    int gx = r % WF;

    const float* xb = x + (size_t)b * 125 * NPIX + r;   // channel stride NPIX
    float tx = xb[(2 * a + 0) * NPIX];
    float ty = xb[(2 * a + 1) * NPIX];
    float tw = xb[(10 + 2 * a) * NPIX];
    float th = xb[(11 + 2 * a) * NPIX];
    float to = xb[(20 + a) * NPIX];

    float sx = sigmoidf_(tx);
    float sy = sigmoidf_(ty);
    float obj = sigmoidf_(to);

    float im_h = im_info[b * 2 + 0];
    float im_w = im_info[b * 2 + 1];

    float bx = ((sx + (float)gx) / (float)WF) * im_w;
    float by = ((sy + (float)gy) / (float)HF) * im_h;
    float bw = ((expf(tw) * c_bias[2 * a + 0]) / (float)WF) * im_w;
    float bh = ((expf(th) * c_bias[2 * a + 1]) / (float)HF) * im_h;

    reinterpret_cast<float4*>(boxes_out)[tid] = make_float4(bx, by, bw, bh);

    // corners exactly as reference computes them from (cx,cy,w,h)
    float x1 = bx - bw * 0.5f, x2 = bx + bw * 0.5f;
    float y1 = by - bh * 0.5f, y2 = by + bh * 0.5f;
    corners[tid] = make_float4(x1, y1, x2, y2);
    areas[tid] = bw * bh;

    // softmax over 20 classes * obj  -> scores[(b*NC + c)*NB + n]
    float cv[NC];
    float m = -1e30f;
    #pragma unroll
    for (int c = 0; c < NC; ++c) {
        cv[c] = xb[(25 + NC * a + c) * NPIX];
        m = fmaxf(m, cv[c]);
    }
    float sum = 0.0f;
    #pragma unroll
    for (int c = 0; c < NC; ++c) {
        cv[c] = expf(cv[c] - m);
        sum += cv[c];
    }
    #pragma unroll
    for (int c = 0; c < NC; ++c) {
        scores[((size_t)b * NC + c) * NB + n] = (cv[c] / sum) * obj;
    }
}

// ---------------------------------------------------------------------------
// Kernel 2: per-batch IoU threshold bitmask, 2 rows per wave (shared column
// loads).  Rows padded to 32 u64 (pad words written as ZERO).
// ---------------------------------------------------------------------------
__global__ __launch_bounds__(64) void iou_mask_kernel(
        const float4* __restrict__ corners, const float* __restrict__ areas,
        u64* __restrict__ M64) {
    int blk = blockIdx.x;              // BB * 903
    int b = blk / 903;
    int i0 = (blk % 903) * 2;
    int i1 = i0 + 1;
    bool has1 = i1 < NB;
    int lane = threadIdx.x;

    const float4* cb = corners + (size_t)b * NB;
    const float* ab = areas + (size_t)b * NB;
    float4 cA = cb[i0];
    float aA = ab[i0];
    float4 cB = cb[has1 ? i1 : i0];
    float aB = ab[has1 ? i1 : i0];

    u64 wordA = 0, wordB = 0;
    #pragma unroll 4
    for (int t = 0; t < NW64; ++t) {
        int j = t * 64 + lane;
        int jc = j < NB ? j : NB - 1;
        float4 cj = cb[jc];
        float ar = ab[jc];

        float iwA = fmaxf(fminf(cA.z, cj.z) - fmaxf(cA.x, cj.x), 0.0f);
        float ihA = fmaxf(fminf(cA.w, cj.w) - fmaxf(cA.y, cj.y), 0.0f);
        float inA = iwA * ihA;
        float dnA = aA + ar - inA + 1e-9f;
        bool pA = ((double)inA > IOU_MID * (double)dnA) && (j < NB);
        u64 mA = __ballot(pA);

        float iwB = fmaxf(fminf(cB.z, cj.z) - fmaxf(cB.x, cj.x), 0.0f);
        float ihB = fmaxf(fminf(cB.w, cj.w) - fmaxf(cB.y, cj.y), 0.0f);
        float inB = iwB * ihB;
        float dnB = aB + ar - inB + 1e-9f;
        bool pB = ((double)inB > IOU_MID * (double)dnB) && (j < NB);
        u64 mB = __ballot(pB);

        if (lane == t) { wordA = mA; wordB = mB; }
    }
    if (lane < MS64) {
        u64 wa = (lane < NW64) ? wordA : 0ull;
        M64[((size_t)b * NB + i0) * MS64 + lane] = wa;
        if (has1) {
            u64 wb = (lane < NW64) ? wordB : 0ull;
            M64[((size_t)b * NB + i1) * MS64 + lane] = wb;
        }
    }
}

// ---------------------------------------------------------------------------
// Kernel 3: stable descending argsort per (b,c) via bitonic sort of u64 keys.
// key = (score_bits << 32) | (2047 - idx); scores strictly > 0 so float bits
// are order-preserving as unsigned.  Padding keys = 0 sort last.
// ---------------------------------------------------------------------------
__global__ __launch_bounds__(512) void sort_kernel(
        const float* __restrict__ scores, u32* __restrict__ order) {
    int bc = blockIdx.x;               // 0 .. NBC-1
    __shared__ u64 keys[2048];
    const float* s = scores + (size_t)bc * NB;

    for (int t = threadIdx.x; t < 2048; t += 512) {
        u64 k = 0;
        if (t < NB) {
            u32 sb = __float_as_uint(s[t]);
            k = ((u64)sb << 32) | (u64)(2047 - t);
        }
        keys[t] = k;
    }
    __syncthreads();

    for (int k = 2; k <= 2048; k <<= 1) {
        for (int j = k >> 1; j > 0; j >>= 1) {
            for (int t = threadIdx.x; t < 2048; t += 512) {
                int ixj = t ^ j;
                if (ixj > t) {
                    u64 a = keys[t], b = keys[ixj];
                    bool desc = ((t & k) == 0);
                    bool sw = desc ? (a < b) : (a > b);
                    if (sw) { keys[t] = b; keys[ixj] = a; }
                }
            }
            __syncthreads();
        }
    }

    for (int t = threadIdx.x; t < NB; t += 512)
        order[(size_t)bc * NB + t] = 2047u - (u32)(keys[t] & 0xFFFFFFFFull);
}

// ---------------------------------------------------------------------------
// Kernel 4: greedy NMS, one wave per (b,c), chunked by 64 sorted candidates.
// (a) 16-instruction width-16 global_load_lds staging (4 rows/inst, row
//     index via one ds_bpermute), double-buffered;
// (b) parallel colmask build (64 independent ds_reads/lane);
// (c) EXACT greedy via O(chain-depth) ballot rounds: a box with no
//     earlier-ranked ACTIVE suppressor is necessarily greedy-kept;
// (d) pipelined rw update from kept rows.
// blockIdx mapping clusters same-batch blocks on one XCD (b = blk % 16).
// ---------------------------------------------------------------------------
__global__ __launch_bounds__(64) void nms_scan_kernel(
        const u32* __restrict__ order, const u32* __restrict__ M32,
        u32* __restrict__ keep) {
    int blk = blockIdx.x;
    int b = blk % BB;            // blk%8 = XCD -> 2 batches per XCD (L2 locality)
    int cls = blk / BB;
    int bc = b * NC + cls;
    int lane = threadIdx.x;
    const u32* ord = order + (size_t)bc * NB;
    const u32* Mb = M32 + (size_t)b * NB * MS32;

    __shared__ u32 rows[2][64 * 64];   // [buf][row d][word], 32 KB
    __shared__ u32 kws[64];
    kws[lane] = 0;

    constexpr int NCHUNK = (NB + 63) / 64;   // 29

    u32 rw = 0;    // removed word (lane w owns word w, w < NW32)

    u32 sidx_cur = ord[lane];          // positions 0..127 all < NB
    u32 sidx_next = ord[64 + lane];

    int sub = lane >> 4;               // row-within-group for staging
    int l16 = lane & 15;

    // stage chunk 0 into buffer 0: 16 insts x (1 bpermute + 16B gll)
    #pragma unroll
    for (int t = 0; t < 16; ++t) {
        int d = t * 4 + sub;
        u32 idx = (u32)__builtin_amdgcn_ds_bpermute(d << 2, (int)sidx_cur);
        idx = idx < NB ? idx : (NB - 1);
        const u32* rowp = Mb + (size_t)idx * MS32 + l16 * 4;
        __builtin_amdgcn_global_load_lds(
            (const __attribute__((address_space(1))) void*)rowp,
            (__attribute__((address_space(3))) void*)&rows[0][t * 256],
            16, 0, 0);
    }
    __syncthreads();

    u64 lt = (1ull << lane) - 1ull;    // bits strictly below my candidate slot

    int cur = 0;
    for (int c = 0; c < NCHUNK; ++c) {
        // stage chunk c+1 into the other buffer (overlaps with work below)
        if (c + 1 < NCHUNK) {
            #pragma unroll
            for (int t = 0; t < 16; ++t) {
                int d = t * 4 + sub;
                u32 idx = (u32)__builtin_amdgcn_ds_bpermute(d << 2, (int)sidx_next);
                idx = idx < NB ? idx : (NB - 1);
                const u32* rowp = Mb + (size_t)idx * MS32 + l16 * 4;
                __builtin_amdgcn_global_load_lds(
                    (const __attribute__((address_space(1))) void*)rowp,
                    (__attribute__((address_space(3))) void*)&rows[cur ^ 1][t * 256],
                    16, 0, 0);
            }
        }
        // prefetch sorted indices for chunk c+2
        u32 sidx_next2 = sidx_next;
        if (c + 2 < NCHUNK) {
            int p = (c + 2) * 64 + lane;
            p = p < NB ? p : (NB - 1);
            sidx_next2 = ord[p];
        }

        u32 idx = sidx_cur < NB ? sidx_cur : (NB - 1);
        u32 we = idx >> 5;
        u32 be = idx & 31u;
        bool valid = (c * 64 + lane) < NB;

        // pre-suppression: bit idx of global removed mask (word we on lane we)
        u32 wv = (u32)__builtin_amdgcn_ds_bpermute((int)(we << 2), (int)rw);
        bool pre = ((wv >> be) & 1u) != 0u;

        // column mask: col bit d = M[idx_d][idx_e]  (independent LDS reads)
        const u32* rbase = &rows[cur][0];
        u32 collo = 0, colhi = 0;
        #pragma unroll
        for (int d = 0; d < 32; ++d) {
            u32 w = rbase[d * 64 + we];
            collo |= ((w >> be) & 1u) << d;
        }
        #pragma unroll
        for (int d = 0; d < 32; ++d) {
            u32 w = rbase[(d + 32) * 64 + we];
            colhi |= ((w >> be) & 1u) << d;
        }
        u64 col = ((u64)colhi << 32) | (u64)collo;

        // exact greedy via ballot rounds (rounds = suppression chain depth)
        u64 act = __ballot(valid && !pre);
        u64 kept = 0;
        while (act) {
            u64 unsafe = __ballot((col & act & lt) != 0ull);
            u64 safe = act & ~unsafe;           // provably greedy-kept
            kept |= safe;
            u64 supp = __ballot((col & safe & lt) != 0ull);
            act &= ~(safe | supp);
        }

        // record kept boxes into the keep bitmask
        if ((kept >> lane) & 1ull) atomicOr(&kws[we], 1u << be);

        // fold kept rows into the global removed mask (pipelined reads;
        // pad words 58..63 are zero in M so lanes 58..63 stay clean)
        u64 km = kept;
        while (km) {
            int d = __builtin_ctzll(km);
            km &= km - 1;
            rw |= rbase[d * 64 + lane];
        }

        __syncthreads();   // drains staging of chunk c+1; orders buffer reuse
        cur ^= 1;
        sidx_cur = sidx_next;
        sidx_next = sidx_next2;
    }
    __syncthreads();
    if (lane < NW32) keep[(size_t)bc * NW32 + lane] = kws[lane];
}

// ---------------------------------------------------------------------------
// Kernel 5: prob[b][n][c] = keep_bit(b,c,n) ? scores[b][c][n] : 0
// ---------------------------------------------------------------------------
__global__ __launch_bounds__(256) void finalize_kernel(
        const float* __restrict__ scores, const u32* __restrict__ keep,
        float* __restrict__ prob) {
    int tid = blockIdx.x * blockDim.x + threadIdx.x;
    if (tid >= PROB_ELEMS) return;
    int c = tid % NC;
    int t2 = tid / NC;
    int n = t2 % NB;
    int b = t2 / NB;
    int bc = b * NC + c;
    u32 w = keep[(size_t)bc * NW32 + (n >> 5)];
    float s = scores[(size_t)bc * NB + n];
    prob[tid] = ((w >> (n & 31)) & 1u) ? s : 0.0f;
}

// ---------------------------------------------------------------------------
extern "C" void kernel_launch(void* const* d_in, const int* in_sizes, int n_in,
                              void* d_out, int out_size, void* d_ws, size_t ws_size,
                              hipStream_t stream) {
    const float* x = (const float*)d_in[0];        // (16,125,19,19)
    const float* im_info = (const float*)d_in[1];  // (16,2)

    float* prob_out = (float*)d_out;                       // 577600 floats
    float* boxes_out = prob_out + PROB_ELEMS;              // 115520 floats

    // workspace layout
    float* scores = (float*)d_ws;                           // 577600 f32
    u32* order = (u32*)(scores + PROB_ELEMS);               // 577600 u32
    // corners+areas alias the `order` region (order is written later, in sort)
    float4* corners = (float4*)order;                       // 28880 float4
    float* areas = (float*)(corners + (size_t)BB * NB);     // 28880 f32
    char* mbase = (char*)d_ws + (size_t)2 * PROB_ELEMS * 4;
    u64* M64 = (u64*)mbase;                                 // 16*1805*32 u64 (padded)
    u32* M32 = (u32*)mbase;
    u32* keep = (u32*)(mbase + (size_t)BB * NB * MS64 * 8); // 320*58 u32

    int nthreads = BB * NB;   // 28880
    decode_kernel<<<(nthreads + 255) / 256, 256, 0, stream>>>(
        x, im_info, boxes_out, corners, areas, scores);

    iou_mask_kernel<<<BB * 903, 64, 0, stream>>>(corners, areas, M64);

    sort_kernel<<<NBC, 512, 0, stream>>>(scores, order);

    nms_scan_kernel<<<NBC, 64, 0, stream>>>(order, M32, keep);

    finalize_kernel<<<(PROB_ELEMS + 255) / 256, 256, 0, stream>>>(
        scores, keep, prob_out);
}

// Round 5
// 214.455 us; speedup vs baseline: 3.5270x; 1.0521x over previous
//
#include <hip/hip_runtime.h>
#include <hip/hip_bf16.h>

typedef unsigned int u32;
typedef unsigned long long u64;

#define BB 16
#define NA 5
#define NC 20
#define HF 19
#define WF 19
#define NPIX 361        // 19*19
#define NB 1805         // NA*NPIX boxes per batch
#define NW32 58         // ceil(1805/32)
#define NW64 29         // ceil(1805/64)
#define MS64 32         // padded M row stride in u64 (256 B rows)
#define MS32 64         // padded M row stride in u32
#define NBC (BB*NC)     // 320 (batch,class) pairs
#define PROB_ELEMS (BB*NB*NC)   // 577600

// Exact-equivalence threshold: RN_f32(inter/denom) > 0.45f
//   <=>  (double)inter > MID * (double)denom
// where MID = midpoint(0.45f, nextup(0.45f)) = 0x1.CCCCCDp-2 (exact in f64;
// 25-bit MID x 24-bit denom product is exact; tie rounds-to-even to 0.45f
// which is NOT > 0.45f, matching the strict > here).
#define IOU_MID 0x1.CCCCCDp-2

__constant__ float c_bias[10] = {1.08f, 1.19f, 3.42f, 4.41f, 6.63f,
                                 11.38f, 9.42f, 5.11f, 16.62f, 10.52f};

__device__ __forceinline__ float sigmoidf_(float v) {
    return 1.0f / (1.0f + expf(-v));
}

// ---------------------------------------------------------------------------
// Kernel 1: decode boxes (-> d_out boxes section), corners+areas (-> ws,
// aliased over the not-yet-written `order` region), scores (-> ws).
// ---------------------------------------------------------------------------
__global__ __launch_bounds__(256) void decode_kernel(
        const float* __restrict__ x, const float* __restrict__ im_info,
        float* __restrict__ boxes_out, float4* __restrict__ corners,
        float* __restrict__ areas, float* __restrict__ scores) {
    int tid = blockIdx.x * blockDim.x + threadIdx.x;
    if (tid >= BB * NB) return;
    int b = tid / NB;
    int n = tid % NB;
    int a = n / NPIX;
    int r = n % NPIX;
    int gy = r / WF;
    int gx = r % WF;

    const float* xb = x + (size_t)b * 125 * NPIX + r;   // channel stride NPIX
    float tx = xb[(2 * a + 0) * NPIX];
    float ty = xb[(2 * a + 1) * NPIX];
    float tw = xb[(10 + 2 * a) * NPIX];
    float th = xb[(11 + 2 * a) * NPIX];
    float to = xb[(20 + a) * NPIX];

    float sx = sigmoidf_(tx);
    float sy = sigmoidf_(ty);
    float obj = sigmoidf_(to);

    float im_h = im_info[b * 2 + 0];
    float im_w = im_info[b * 2 + 1];

    float bx = ((sx + (float)gx) / (float)WF) * im_w;
    float by = ((sy + (float)gy) / (float)HF) * im_h;
    float bw = ((expf(tw) * c_bias[2 * a + 0]) / (float)WF) * im_w;
    float bh = ((expf(th) * c_bias[2 * a + 1]) / (float)HF) * im_h;

    reinterpret_cast<float4*>(boxes_out)[tid] = make_float4(bx, by, bw, bh);

    // corners exactly as reference computes them from (cx,cy,w,h)
    float x1 = bx - bw * 0.5f, x2 = bx + bw * 0.5f;
    float y1 = by - bh * 0.5f, y2 = by + bh * 0.5f;
    corners[tid] = make_float4(x1, y1, x2, y2);
    areas[tid] = bw * bh;

    // softmax over 20 classes * obj  -> scores[(b*NC + c)*NB + n]
    float cv[NC];
    float m = -1e30f;
    #pragma unroll
    for (int c = 0; c < NC; ++c) {
        cv[c] = xb[(25 + NC * a + c) * NPIX];
        m = fmaxf(m, cv[c]);
    }
    float sum = 0.0f;
    #pragma unroll
    for (int c = 0; c < NC; ++c) {
        cv[c] = expf(cv[c] - m);
        sum += cv[c];
    }
    #pragma unroll
    for (int c = 0; c < NC; ++c) {
        scores[((size_t)b * NC + c) * NB + n] = (cv[c] / sum) * obj;
    }
}

// ---------------------------------------------------------------------------
// Kernel 2: per-batch IoU threshold bitmask, 4 rows per wave (shared column
// loads + ballots).  Rows padded to 32 u64 (pad words written as ZERO).
// ---------------------------------------------------------------------------
__global__ __launch_bounds__(64) void iou_mask_kernel(
        const float4* __restrict__ corners, const float* __restrict__ areas,
        u64* __restrict__ M64) {
    int blk = blockIdx.x;              // BB * 452
    int b = blk / 452;
    int i0 = (blk % 452) * 4;
    int lane = threadIdx.x;

    const float4* cb = corners + (size_t)b * NB;
    const float* ab = areas + (size_t)b * NB;

    float4 cr[4];
    float arr[4];
    #pragma unroll
    for (int q = 0; q < 4; ++q) {
        int iq = i0 + q < NB ? i0 + q : NB - 1;
        cr[q] = cb[iq];
        arr[q] = ab[iq];
    }

    u64 word[4] = {0, 0, 0, 0};
    for (int t = 0; t < NW64; ++t) {
        int j = t * 64 + lane;
        int jc = j < NB ? j : NB - 1;
        float4 cj = cb[jc];
        float ar = ab[jc];
        #pragma unroll
        for (int q = 0; q < 4; ++q) {
            float iw = fmaxf(fminf(cr[q].z, cj.z) - fmaxf(cr[q].x, cj.x), 0.0f);
            float ih = fmaxf(fminf(cr[q].w, cj.w) - fmaxf(cr[q].y, cj.y), 0.0f);
            float in = iw * ih;
            float dn = arr[q] + ar - in + 1e-9f;
            bool p = ((double)in > IOU_MID * (double)dn) && (j < NB);
            u64 m = __ballot(p);
            if (lane == t) word[q] = m;
        }
    }
    if (lane < MS64) {
        #pragma unroll
        for (int q = 0; q < 4; ++q) {
            int iq = i0 + q;
            if (iq < NB) {
                u64 w = (lane < NW64) ? word[q] : 0ull;
                M64[((size_t)b * NB + iq) * MS64 + lane] = w;
            }
        }
    }
}

// ---------------------------------------------------------------------------
// Kernel 3: stable descending argsort per (b,c) via bitonic sort of u64 keys.
// key = (score_bits << 32) | (2047 - idx); scores strictly > 0 so float bits
// are order-preserving as unsigned.  Padding keys = 0 sort last.
// ---------------------------------------------------------------------------
__global__ __launch_bounds__(512) void sort_kernel(
        const float* __restrict__ scores, u32* __restrict__ order) {
    int bc = blockIdx.x;               // 0 .. NBC-1
    __shared__ u64 keys[2048];
    const float* s = scores + (size_t)bc * NB;

    for (int t = threadIdx.x; t < 2048; t += 512) {
        u64 k = 0;
        if (t < NB) {
            u32 sb = __float_as_uint(s[t]);
            k = ((u64)sb << 32) | (u64)(2047 - t);
        }
        keys[t] = k;
    }
    __syncthreads();

    for (int k = 2; k <= 2048; k <<= 1) {
        for (int j = k >> 1; j > 0; j >>= 1) {
            for (int t = threadIdx.x; t < 2048; t += 512) {
                int ixj = t ^ j;
                if (ixj > t) {
                    u64 a = keys[t], b = keys[ixj];
                    bool desc = ((t & k) == 0);
                    bool sw = desc ? (a < b) : (a > b);
                    if (sw) { keys[t] = b; keys[ixj] = a; }
                }
            }
            __syncthreads();
        }
    }

    for (int t = threadIdx.x; t < NB; t += 512)
        order[(size_t)bc * NB + t] = 2047u - (u32)(keys[t] & 0xFFFFFFFFull);
}

// ---------------------------------------------------------------------------
// Kernel 4: greedy NMS, one wave per (b,c), chunked by 64 sorted candidates.
// (a) 16-instruction width-16 global_load_lds staging (4 rows/inst), dbuf;
// (b) parallel colmask build (64 independent ds_reads/lane);
// (c) EXACT greedy via O(chain-depth) ballot rounds;
// (d) BRANCHLESS rw update: 64 independent gated ds_reads (bank-conflict-
//     free, pipelined) instead of a serial per-kept-row latency chain.
// blockIdx mapping clusters same-batch blocks on one XCD (b = blk % 16).
// ---------------------------------------------------------------------------
__global__ __launch_bounds__(64) void nms_scan_kernel(
        const u32* __restrict__ order, const u32* __restrict__ M32,
        u32* __restrict__ keep) {
    int blk = blockIdx.x;
    int b = blk % BB;            // blk%8 = XCD -> 2 batches per XCD (L2 locality)
    int cls = blk / BB;
    int bc = b * NC + cls;
    int lane = threadIdx.x;
    const u32* ord = order + (size_t)bc * NB;
    const u32* Mb = M32 + (size_t)b * NB * MS32;

    __shared__ u32 rows[2][64 * 64];   // [buf][row d][word], 32 KB
    __shared__ u32 kws[64];
    kws[lane] = 0;

    constexpr int NCHUNK = (NB + 63) / 64;   // 29

    u32 rw = 0;    // removed word (lane w owns word w, w < NW32)

    u32 sidx_cur = ord[lane];          // positions 0..127 all < NB
    u32 sidx_next = ord[64 + lane];

    int sub = lane >> 4;               // row-within-group for staging
    int l16 = lane & 15;

    // stage chunk 0 into buffer 0: 16 insts x (1 bpermute + 16B gll)
    #pragma unroll
    for (int t = 0; t < 16; ++t) {
        int d = t * 4 + sub;
        u32 idx = (u32)__builtin_amdgcn_ds_bpermute(d << 2, (int)sidx_cur);
        idx = idx < NB ? idx : (NB - 1);
        const u32* rowp = Mb + (size_t)idx * MS32 + l16 * 4;
        __builtin_amdgcn_global_load_lds(
            (const __attribute__((address_space(1))) void*)rowp,
            (__attribute__((address_space(3))) void*)&rows[0][t * 256],
            16, 0, 0);
    }
    __syncthreads();

    u64 lt = (1ull << lane) - 1ull;    // bits strictly below my candidate slot

    int cur = 0;
    for (int c = 0; c < NCHUNK; ++c) {
        // stage chunk c+1 into the other buffer (overlaps with work below)
        if (c + 1 < NCHUNK) {
            #pragma unroll
            for (int t = 0; t < 16; ++t) {
                int d = t * 4 + sub;
                u32 idx = (u32)__builtin_amdgcn_ds_bpermute(d << 2, (int)sidx_next);
                idx = idx < NB ? idx : (NB - 1);
                const u32* rowp = Mb + (size_t)idx * MS32 + l16 * 4;
                __builtin_amdgcn_global_load_lds(
                    (const __attribute__((address_space(1))) void*)rowp,
                    (__attribute__((address_space(3))) void*)&rows[cur ^ 1][t * 256],
                    16, 0, 0);
            }
        }
        // prefetch sorted indices for chunk c+2
        u32 sidx_next2 = sidx_next;
        if (c + 2 < NCHUNK) {
            int p = (c + 2) * 64 + lane;
            p = p < NB ? p : (NB - 1);
            sidx_next2 = ord[p];
        }

        u32 idx = sidx_cur < NB ? sidx_cur : (NB - 1);
        u32 we = idx >> 5;
        u32 be = idx & 31u;
        bool valid = (c * 64 + lane) < NB;

        // pre-suppression: bit idx of global removed mask (word we on lane we)
        u32 wv = (u32)__builtin_amdgcn_ds_bpermute((int)(we << 2), (int)rw);
        bool pre = ((wv >> be) & 1u) != 0u;

        // column mask: col bit d = M[idx_d][idx_e]  (independent LDS reads)
        const u32* rbase = &rows[cur][0];
        u32 collo = 0, colhi = 0;
        #pragma unroll
        for (int d = 0; d < 32; ++d) {
            u32 w = rbase[d * 64 + we];
            collo |= ((w >> be) & 1u) << d;
        }
        #pragma unroll
        for (int d = 0; d < 32; ++d) {
            u32 w = rbase[(d + 32) * 64 + we];
            colhi |= ((w >> be) & 1u) << d;
        }
        u64 col = ((u64)colhi << 32) | (u64)collo;

        // exact greedy via ballot rounds (rounds = suppression chain depth)
        u64 act = __ballot(valid && !pre);
        u64 kept = 0;
        while (act) {
            u64 unsafe = __ballot((col & act & lt) != 0ull);
            u64 safe = act & ~unsafe;           // provably greedy-kept
            kept |= safe;
            u64 supp = __ballot((col & safe & lt) != 0ull);
            act &= ~(safe | supp);
        }

        // record kept boxes into the keep bitmask
        if ((kept >> lane) & 1ull) atomicOr(&kws[we], 1u << be);

        // fold kept rows into the global removed mask: branchless gated OR,
        // 64 independent conflict-free ds_reads (pad words 58..63 are zero)
        u32 klo = (u32)kept, khi = (u32)(kept >> 32);
        #pragma unroll
        for (int d = 0; d < 32; ++d) {
            u32 g = 0u - ((klo >> d) & 1u);
            rw |= rbase[d * 64 + lane] & g;
        }
        #pragma unroll
        for (int d = 0; d < 32; ++d) {
            u32 g = 0u - ((khi >> d) & 1u);
            rw |= rbase[(d + 32) * 64 + lane] & g;
        }

        __syncthreads();   // drains staging of chunk c+1; orders buffer reuse
        cur ^= 1;
        sidx_cur = sidx_next;
        sidx_next = sidx_next2;
    }
    __syncthreads();
    if (lane < NW32) keep[(size_t)bc * NW32 + lane] = kws[lane];
}

// ---------------------------------------------------------------------------
// Kernel 5: prob[b][n][c] = keep_bit(b,c,n) ? scores[b][c][n] : 0
// ---------------------------------------------------------------------------
__global__ __launch_bounds__(256) void finalize_kernel(
        const float* __restrict__ scores, const u32* __restrict__ keep,
        float* __restrict__ prob) {
    int tid = blockIdx.x * blockDim.x + threadIdx.x;
    if (tid >= PROB_ELEMS) return;
    int c = tid % NC;
    int t2 = tid / NC;
    int n = t2 % NB;
    int b = t2 / NB;
    int bc = b * NC + c;
    u32 w = keep[(size_t)bc * NW32 + (n >> 5)];
    float s = scores[(size_t)bc * NB + n];
    prob[tid] = ((w >> (n & 31)) & 1u) ? s : 0.0f;
}

// ---------------------------------------------------------------------------
extern "C" void kernel_launch(void* const* d_in, const int* in_sizes, int n_in,
                              void* d_out, int out_size, void* d_ws, size_t ws_size,
                              hipStream_t stream) {
    const float* x = (const float*)d_in[0];        // (16,125,19,19)
    const float* im_info = (const float*)d_in[1];  // (16,2)

    float* prob_out = (float*)d_out;                       // 577600 floats
    float* boxes_out = prob_out + PROB_ELEMS;              // 115520 floats

    // workspace layout
    float* scores = (float*)d_ws;                           // 577600 f32
    u32* order = (u32*)(scores + PROB_ELEMS);               // 577600 u32
    // corners+areas alias the `order` region (order is written later, in sort)
    float4* corners = (float4*)order;                       // 28880 float4
    float* areas = (float*)(corners + (size_t)BB * NB);     // 28880 f32
    char* mbase = (char*)d_ws + (size_t)2 * PROB_ELEMS * 4;
    u64* M64 = (u64*)mbase;                                 // 16*1805*32 u64 (padded)
    u32* M32 = (u32*)mbase;
    u32* keep = (u32*)(mbase + (size_t)BB * NB * MS64 * 8); // 320*58 u32

    int nthreads = BB * NB;   // 28880
    decode_kernel<<<(nthreads + 255) / 256, 256, 0, stream>>>(
        x, im_info, boxes_out, corners, areas, scores);

    iou_mask_kernel<<<BB * 452, 64, 0, stream>>>(corners, areas, M64);

    sort_kernel<<<NBC, 512, 0, stream>>>(scores, order);

    nms_scan_kernel<<<NBC, 64, 0, stream>>>(order, M32, keep);

    finalize_kernel<<<(PROB_ELEMS + 255) / 256, 256, 0, stream>>>(
        scores, keep, prob_out);
}

// Round 6
// 186.926 us; speedup vs baseline: 4.0464x; 1.1473x over previous
//
#include <hip/hip_runtime.h>
#include <hip/hip_bf16.h>

typedef unsigned int u32;
typedef unsigned long long u64;

#define BB 16
#define NA 5
#define NC 20
#define HF 19
#define WF 19
#define NPIX 361        // 19*19
#define NB 1805         // NA*NPIX boxes per batch
#define NW32 58         // ceil(1805/32)
#define NW64 29         // ceil(1805/64)
#define MS64 32         // padded M row stride in u64 (256 B rows)
#define MS32 64         // padded M row stride in u32
#define NBC (BB*NC)     // 320 (batch,class) pairs
#define PROB_ELEMS (BB*NB*NC)   // 577600
#define NCHUNK 29       // ceil(NB/64)

// Exact-equivalence threshold: RN_f32(inter/denom) > 0.45f
//   <=>  (double)inter > MID * (double)denom
// where MID = midpoint(0.45f, nextup(0.45f)) = 0x1.CCCCCDp-2 (exact in f64;
// 25-bit MID x 24-bit denom product is exact; tie rounds-to-even to 0.45f
// which is NOT > 0.45f, matching the strict > here).
#define IOU_MID 0x1.CCCCCDp-2

__constant__ float c_bias[10] = {1.08f, 1.19f, 3.42f, 4.41f, 6.63f,
                                 11.38f, 9.42f, 5.11f, 16.62f, 10.52f};

__device__ __forceinline__ float sigmoidf_(float v) {
    return 1.0f / (1.0f + expf(-v));
}

// ---------------------------------------------------------------------------
// Kernel 1: decode boxes (-> d_out boxes section), corners+areas (-> ws,
// aliased over the not-yet-written `order` region), scores (-> ws).
// ---------------------------------------------------------------------------
__global__ __launch_bounds__(256) void decode_kernel(
        const float* __restrict__ x, const float* __restrict__ im_info,
        float* __restrict__ boxes_out, float4* __restrict__ corners,
        float* __restrict__ areas, float* __restrict__ scores) {
    int tid = blockIdx.x * blockDim.x + threadIdx.x;
    if (tid >= BB * NB) return;
    int b = tid / NB;
    int n = tid % NB;
    int a = n / NPIX;
    int r = n % NPIX;
    int gy = r / WF;
    int gx = r % WF;

    const float* xb = x + (size_t)b * 125 * NPIX + r;   // channel stride NPIX
    float tx = xb[(2 * a + 0) * NPIX];
    float ty = xb[(2 * a + 1) * NPIX];
    float tw = xb[(10 + 2 * a) * NPIX];
    float th = xb[(11 + 2 * a) * NPIX];
    float to = xb[(20 + a) * NPIX];

    float sx = sigmoidf_(tx);
    float sy = sigmoidf_(ty);
    float obj = sigmoidf_(to);

    float im_h = im_info[b * 2 + 0];
    float im_w = im_info[b * 2 + 1];

    float bx = ((sx + (float)gx) / (float)WF) * im_w;
    float by = ((sy + (float)gy) / (float)HF) * im_h;
    float bw = ((expf(tw) * c_bias[2 * a + 0]) / (float)WF) * im_w;
    float bh = ((expf(th) * c_bias[2 * a + 1]) / (float)HF) * im_h;

    reinterpret_cast<float4*>(boxes_out)[tid] = make_float4(bx, by, bw, bh);

    // corners exactly as reference computes them from (cx,cy,w,h)
    float x1 = bx - bw * 0.5f, x2 = bx + bw * 0.5f;
    float y1 = by - bh * 0.5f, y2 = by + bh * 0.5f;
    corners[tid] = make_float4(x1, y1, x2, y2);
    areas[tid] = bw * bh;

    // softmax over 20 classes * obj  -> scores[(b*NC + c)*NB + n]
    float cv[NC];
    float m = -1e30f;
    #pragma unroll
    for (int c = 0; c < NC; ++c) {
        cv[c] = xb[(25 + NC * a + c) * NPIX];
        m = fmaxf(m, cv[c]);
    }
    float sum = 0.0f;
    #pragma unroll
    for (int c = 0; c < NC; ++c) {
        cv[c] = expf(cv[c] - m);
        sum += cv[c];
    }
    #pragma unroll
    for (int c = 0; c < NC; ++c) {
        scores[((size_t)b * NC + c) * NB + n] = (cv[c] / sum) * obj;
    }
}

// ---------------------------------------------------------------------------
// Kernel 2: per-batch IoU threshold bitmask, 4 rows per wave (shared column
// loads + ballots).  Rows padded to 32 u64 (pad words written as ZERO).
// ---------------------------------------------------------------------------
__global__ __launch_bounds__(64) void iou_mask_kernel(
        const float4* __restrict__ corners, const float* __restrict__ areas,
        u64* __restrict__ M64) {
    int blk = blockIdx.x;              // BB * 452
    int b = blk / 452;
    int i0 = (blk % 452) * 4;
    int lane = threadIdx.x;

    const float4* cb = corners + (size_t)b * NB;
    const float* ab = areas + (size_t)b * NB;

    float4 cr[4];
    float arr[4];
    #pragma unroll
    for (int q = 0; q < 4; ++q) {
        int iq = i0 + q < NB ? i0 + q : NB - 1;
        cr[q] = cb[iq];
        arr[q] = ab[iq];
    }

    u64 word[4] = {0, 0, 0, 0};
    for (int t = 0; t < NW64; ++t) {
        int j = t * 64 + lane;
        int jc = j < NB ? j : NB - 1;
        float4 cj = cb[jc];
        float ar = ab[jc];
        #pragma unroll
        for (int q = 0; q < 4; ++q) {
            float iw = fmaxf(fminf(cr[q].z, cj.z) - fmaxf(cr[q].x, cj.x), 0.0f);
            float ih = fmaxf(fminf(cr[q].w, cj.w) - fmaxf(cr[q].y, cj.y), 0.0f);
            float in = iw * ih;
            float dn = arr[q] + ar - in + 1e-9f;
            bool p = ((double)in > IOU_MID * (double)dn) && (j < NB);
            u64 m = __ballot(p);
            if (lane == t) word[q] = m;
        }
    }
    if (lane < MS64) {
        #pragma unroll
        for (int q = 0; q < 4; ++q) {
            int iq = i0 + q;
            if (iq < NB) {
                u64 w = (lane < NW64) ? word[q] : 0ull;
                M64[((size_t)b * NB + iq) * MS64 + lane] = w;
            }
        }
    }
}

// ---------------------------------------------------------------------------
// Kernel 3: stable descending argsort per (b,c) — hybrid register/LDS bitonic
// on 2048 u64 keys.  Identical comparator network to the pure-LDS version
// (bit-identical output), but all strides j<=128 run in registers: each wave
// owns a 256-element segment (4 regs/lane; e = w*256 + i*64 + lane), j<=32
// via shfl_xor, j=64/128 via register exchange.  LDS passes only for j>=256.
// key = (score_bits << 32) | (2047 - idx); scores strictly > 0.
// ---------------------------------------------------------------------------
__device__ __forceinline__ u64 shfl_xor_u64(u64 v, int m) {
    u32 lo = (u32)v, hi = (u32)(v >> 32);
    lo = (u32)__shfl_xor((int)lo, m, 64);
    hi = (u32)__shfl_xor((int)hi, m, 64);
    return ((u64)hi << 32) | lo;
}

__global__ __launch_bounds__(512) void sort_kernel(
        const float* __restrict__ scores, u32* __restrict__ order) {
    int bc = blockIdx.x;               // 0 .. NBC-1
    __shared__ u64 keys[2048];
    const float* s = scores + (size_t)bc * NB;
    int tid = threadIdx.x;
    int lane = tid & 63;
    int w = tid >> 6;
    int base = w * 256;

    u64 r[4];
    #pragma unroll
    for (int i = 0; i < 4; ++i) {
        int e = base + i * 64 + lane;
        u64 k = 0;
        if (e < NB) {
            u32 sb = __float_as_uint(s[e]);
            k = ((u64)sb << 32) | (u64)(2047 - e);
        }
        r[i] = k;
    }

    // register exchange between regs ia < ib (element stride 64 or 128)
    auto rexch = [&](int k, int ia, int ib) {
        int e = base + ia * 64 + lane;           // lower element index
        bool desc = ((e & k) == 0);
        u64 a = r[ia], b = r[ib];
        u64 mx = a > b ? a : b, mn = a > b ? b : a;
        r[ia] = desc ? mx : mn;
        r[ib] = desc ? mn : mx;
    };
    // shuffle stage, stride j <= 32
    auto shstage = [&](int k, int j) {
        #pragma unroll
        for (int i = 0; i < 4; ++i) {
            int e = base + i * 64 + lane;
            u64 p = shfl_xor_u64(r[i], j);
            bool desc = ((e & k) == 0);
            bool upper = (lane & j) != 0;
            bool takemax = desc ^ upper;         // lower idx takes max when desc
            u64 a = r[i];
            u64 mx = a > p ? a : p, mn = a > p ? p : a;
            r[i] = takemax ? mx : mn;
        }
    };
    // all j<=128 stages of phase k
    auto regsession = [&](int k) {
        if (k >= 256) { rexch(k, 0, 2); rexch(k, 1, 3); }   // j=128
        if (k >= 128) { rexch(k, 0, 1); rexch(k, 2, 3); }   // j=64
        int j0 = (k <= 64) ? (k >> 1) : 32;
        for (int j = j0; j >= 1; j >>= 1) shstage(k, j);
    };
    auto store_regs = [&]() {
        #pragma unroll
        for (int i = 0; i < 4; ++i) keys[base + i * 64 + lane] = r[i];
    };
    auto load_regs = [&]() {
        #pragma unroll
        for (int i = 0; i < 4; ++i) r[i] = keys[base + i * 64 + lane];
    };
    // LDS pass for stride j >= 256 (1024 disjoint comparators, 2/thread)
    auto ldspass = [&](int k, int j) {
        #pragma unroll
        for (int h = 0; h < 2; ++h) {
            int m = tid + h * 512;
            int i1 = (m / j) * 2 * j + (m % j);
            int i2 = i1 + j;
            u64 a = keys[i1], b = keys[i2];
            bool desc = ((i1 & k) == 0);
            bool sw = desc ? (a < b) : (a > b);
            if (sw) { keys[i1] = b; keys[i2] = a; }
        }
        __syncthreads();
    };

    // phases k=2..256: fully in registers, no barriers
    for (int k = 2; k <= 256; k <<= 1) regsession(k);
    store_regs(); __syncthreads();

    // k=512
    ldspass(512, 256);
    load_regs(); regsession(512);
    store_regs(); __syncthreads();

    // k=1024
    ldspass(1024, 512); ldspass(1024, 256);
    load_regs(); regsession(1024);
    store_regs(); __syncthreads();

    // k=2048
    ldspass(2048, 1024); ldspass(2048, 512); ldspass(2048, 256);
    load_regs(); regsession(2048);

    #pragma unroll
    for (int i = 0; i < 4; ++i) {
        int e = base + i * 64 + lane;
        if (e < NB)
            order[(size_t)bc * NB + e] = 2047u - (u32)(r[i] & 0xFFFFFFFFull);
    }
}

// ---------------------------------------------------------------------------
// Kernel 4: greedy NMS, one wave per (b,c), chunked by 64 sorted candidates.
// Sorted order preloaded to LDS (kills the bpermute->wait staging chain);
// colmask and OR words each load into fully-unrolled 64-reg arrays so all
// 64 ds_reads issue before one wait.  16-inst width-16 gll staging, dbuf.
// Exact greedy via O(chain-depth) ballot rounds; branchless gated OR update.
// blockIdx mapping clusters same-batch blocks on one XCD (b = blk % 16).
// ---------------------------------------------------------------------------
__global__ __launch_bounds__(64, 1) void nms_scan_kernel(
        const u32* __restrict__ order, const u32* __restrict__ M32,
        u32* __restrict__ keep) {
    int blk = blockIdx.x;
    int b = blk % BB;            // blk%8 = XCD -> 2 batches per XCD (L2 locality)
    int cls = blk / BB;
    int bc = b * NC + cls;
    int lane = threadIdx.x;
    const u32* ord = order + (size_t)bc * NB;
    const u32* Mb = M32 + (size_t)b * NB * MS32;

    __shared__ u32 rows[2][64 * 64];   // [buf][row d][word], 32 KB
    __shared__ u32 sord[NCHUNK * 64];  // 1856 sorted indices (clamped)
    __shared__ u32 kws[64];
    kws[lane] = 0;

    for (int t = lane; t < NCHUNK * 64; t += 64)
        sord[t] = (t < NB) ? ord[t] : (u32)(NB - 1);
    __syncthreads();

    int sub = lane >> 4;               // row-within-group for staging
    int l16 = lane & 15;

    // stage chunk 0 into buffer 0: 16 idx ds_reads (one wait) + 16 glls
    {
        u32 ridx[16];
        #pragma unroll
        for (int t = 0; t < 16; ++t) ridx[t] = sord[t * 4 + sub];
        #pragma unroll
        for (int t = 0; t < 16; ++t) {
            const u32* rowp = Mb + (size_t)ridx[t] * MS32 + l16 * 4;
            __builtin_amdgcn_global_load_lds(
                (const __attribute__((address_space(1))) void*)rowp,
                (__attribute__((address_space(3))) void*)&rows[0][t * 256],
                16, 0, 0);
        }
    }
    __syncthreads();

    u64 lt = (1ull << lane) - 1ull;    // bits strictly below my candidate slot
    u32 rw = 0;                        // removed word (lane w owns word w)

    int cur = 0;
    for (int c = 0; c < NCHUNK; ++c) {
        // stage chunk c+1 into the other buffer (overlaps with work below)
        if (c + 1 < NCHUNK) {
            u32 ridx[16];
            #pragma unroll
            for (int t = 0; t < 16; ++t)
                ridx[t] = sord[(c + 1) * 64 + t * 4 + sub];
            #pragma unroll
            for (int t = 0; t < 16; ++t) {
                const u32* rowp = Mb + (size_t)ridx[t] * MS32 + l16 * 4;
                __builtin_amdgcn_global_load_lds(
                    (const __attribute__((address_space(1))) void*)rowp,
                    (__attribute__((address_space(3))) void*)&rows[cur ^ 1][t * 256],
                    16, 0, 0);
            }
        }

        u32 idx = sord[c * 64 + lane];
        u32 we = idx >> 5;
        u32 be = idx & 31u;
        bool valid = (c * 64 + lane) < NB;

        // pre-suppression: bit idx of global removed mask (word we on lane we)
        u32 wv = (u32)__builtin_amdgcn_ds_bpermute((int)(we << 2), (int)rw);
        bool pre = ((wv >> be) & 1u) != 0u;

        // batched loads: colmask words (by we) and OR words (by lane)
        const u32* rbase = &rows[cur][0];
        u32 wcol[64], wor[64];
        #pragma unroll
        for (int d = 0; d < 64; ++d) wcol[d] = rbase[d * 64 + we];
        #pragma unroll
        for (int d = 0; d < 64; ++d) wor[d] = rbase[d * 64 + lane];

        // column mask: col bit d = M[idx_d][idx_e]
        u32 collo = 0, colhi = 0;
        #pragma unroll
        for (int d = 0; d < 32; ++d) collo |= ((wcol[d] >> be) & 1u) << d;
        #pragma unroll
        for (int d = 0; d < 32; ++d) colhi |= ((wcol[d + 32] >> be) & 1u) << d;
        u64 col = ((u64)colhi << 32) | (u64)collo;

        // exact greedy via ballot rounds (rounds = suppression chain depth)
        u64 act = __ballot(valid && !pre);
        u64 kept = 0;
        while (act) {
            u64 unsafe = __ballot((col & act & lt) != 0ull);
            u64 safe = act & ~unsafe;           // provably greedy-kept
            kept |= safe;
            u64 supp = __ballot((col & safe & lt) != 0ull);
            act &= ~(safe | supp);
        }

        // record kept boxes into the keep bitmask
        if ((kept >> lane) & 1ull) atomicOr(&kws[we], 1u << be);

        // fold kept rows into removed mask: branchless gated OR
        u32 klo = (u32)kept, khi = (u32)(kept >> 32);
        #pragma unroll
        for (int d = 0; d < 32; ++d)
            rw |= wor[d] & (0u - ((klo >> d) & 1u));
        #pragma unroll
        for (int d = 0; d < 32; ++d)
            rw |= wor[d + 32] & (0u - ((khi >> d) & 1u));

        __syncthreads();   // drains staging of chunk c+1; orders buffer reuse
        cur ^= 1;
    }
    __syncthreads();
    if (lane < NW32) keep[(size_t)bc * NW32 + lane] = kws[lane];
}

// ---------------------------------------------------------------------------
// Kernel 5: prob[b][n][c] = keep_bit(b,c,n) ? scores[b][c][n] : 0
// ---------------------------------------------------------------------------
__global__ __launch_bounds__(256) void finalize_kernel(
        const float* __restrict__ scores, const u32* __restrict__ keep,
        float* __restrict__ prob) {
    int tid = blockIdx.x * blockDim.x + threadIdx.x;
    if (tid >= PROB_ELEMS) return;
    int c = tid % NC;
    int t2 = tid / NC;
    int n = t2 % NB;
    int b = t2 / NB;
    int bc = b * NC + c;
    u32 w = keep[(size_t)bc * NW32 + (n >> 5)];
    float s = scores[(size_t)bc * NB + n];
    prob[tid] = ((w >> (n & 31)) & 1u) ? s : 0.0f;
}

// ---------------------------------------------------------------------------
extern "C" void kernel_launch(void* const* d_in, const int* in_sizes, int n_in,
                              void* d_out, int out_size, void* d_ws, size_t ws_size,
                              hipStream_t stream) {
    const float* x = (const float*)d_in[0];        // (16,125,19,19)
    const float* im_info = (const float*)d_in[1];  // (16,2)

    float* prob_out = (float*)d_out;                       // 577600 floats
    float* boxes_out = prob_out + PROB_ELEMS;              // 115520 floats

    // workspace layout
    float* scores = (float*)d_ws;                           // 577600 f32
    u32* order = (u32*)(scores + PROB_ELEMS);               // 577600 u32
    // corners+areas alias the `order` region (order is written later, in sort)
    float4* corners = (float4*)order;                       // 28880 float4
    float* areas = (float*)(corners + (size_t)BB * NB);     // 28880 f32
    char* mbase = (char*)d_ws + (size_t)2 * PROB_ELEMS * 4;
    u64* M64 = (u64*)mbase;                                 // 16*1805*32 u64 (padded)
    u32* M32 = (u32*)mbase;
    u32* keep = (u32*)(mbase + (size_t)BB * NB * MS64 * 8); // 320*58 u32

    int nthreads = BB * NB;   // 28880
    decode_kernel<<<(nthreads + 255) / 256, 256, 0, stream>>>(
        x, im_info, boxes_out, corners, areas, scores);

    iou_mask_kernel<<<BB * 452, 64, 0, stream>>>(corners, areas, M64);

    sort_kernel<<<NBC, 512, 0, stream>>>(scores, order);

    nms_scan_kernel<<<NBC, 64, 0, stream>>>(order, M32, keep);

    finalize_kernel<<<(PROB_ELEMS + 255) / 256, 256, 0, stream>>>(
        scores, keep, prob_out);
}